// Round 7
// baseline (102.751 us; speedup 1.0000x reference)
//
#include <hip/hip_runtime.h>

#define G_GEN 65
#define FEAT  8192     // 32*16*16
#define NSTAT 32       // stats+base blocks (32*256 = 8192 features)
#define NFILL 2048     // eps zero-fill blocks (128 KB contiguous chunk each)

typedef float f32x4 __attribute__((ext_vector_type(4)));

// Kernel A: three block roles, NO cross-block sync.
//  bid <  32 : per-feature stats -> base rows (R5-proven path)
//  bid == 32 : redundant full recompute -> global rank map rowCol/rowVal (hidden under fill)
//  bid >  32 : zero-fill contiguous 128 KB chunk of the eps block (R5-proven path)
__global__ void __launch_bounds__(256, 8) kA(
    const float* __restrict__ x, const float* __restrict__ lambdas,
    int* __restrict__ rowCol, float* __restrict__ rowVal,
    float* __restrict__ out)
{
    const int bid = blockIdx.x;
    const int t   = threadIdx.x;

    if (bid < NSTAT) {
        // ---- stats + base rows ----
        const int f = bid * 256 + t;          // coalesced across lanes
        float c = x[f];                       // generator 0 = center
        float r = 0.f;
        #pragma unroll 8
        for (int g = 1; g < G_GEN; ++g) r += fabsf(x[g * FEAT + f]);
        float l = c - r, u = c + r;
        bool zero_m = (u <= 0.f);
        bool cross  = (!zero_m) && (l < 0.f);
        float d     = u - l;
        float denom = (d > 0.f) ? d : 1.f;
        float slope = u / denom;
        float lam   = lambdas[f];
        float val   = (lam >= slope) ? (-l * lam * 0.5f) : (u * (1.f - lam) * 0.5f);
        val = cross ? val : 0.f;
        float scale = zero_m ? 0.f : (cross ? lam : 1.f);
        out[f] = c * scale + val;             // g == 0 row
        #pragma unroll 8
        for (int g = 1; g < G_GEN; ++g)
            out[g * FEAT + f] = x[g * FEAT + f] * scale;   // 2nd x read: L2-hot
    } else if (bid == NSTAT) {
        // ---- map block: 32 features/thread, two passes to cap VGPRs ----
        __shared__ int sums[256];
        const int f0 = t * 32;
        float rr[32];
        #pragma unroll
        for (int i = 0; i < 32; ++i) rr[i] = 0.f;
        for (int g = 1; g < G_GEN; ++g) {
            const f32x4* xp = reinterpret_cast<const f32x4*>(x + (size_t)g * FEAT + f0);
            #pragma unroll
            for (int q = 0; q < 8; ++q) {
                f32x4 v = xp[q];
                rr[q*4+0] += fabsf(v[0]); rr[q*4+1] += fabsf(v[1]);
                rr[q*4+2] += fabsf(v[2]); rr[q*4+3] += fabsf(v[3]);
            }
        }
        // pass 1: cross flags as a bitmask + count (no val kept -> low regs)
        unsigned int mask = 0u;
        int cnt = 0;
        {
            const f32x4* cp = reinterpret_cast<const f32x4*>(x + f0);
            #pragma unroll
            for (int q = 0; q < 8; ++q) {
                f32x4 cv = cp[q];
                #pragma unroll
                for (int e = 0; e < 4; ++e) {
                    int i = q*4 + e;
                    float c = cv[e], r = rr[i];
                    float l = c - r, u = c + r;
                    bool cross = (u > 0.f) && (l < 0.f);
                    mask |= (cross ? 1u : 0u) << i;
                    cnt  += cross ? 1 : 0;
                }
            }
        }
        sums[t] = cnt;
        __syncthreads();
        for (int off = 1; off < 256; off <<= 1) {
            int v   = sums[t];
            int add = (t >= off) ? sums[t - off] : 0;
            __syncthreads();
            sums[t] = v + add;
            __syncthreads();
        }
        int rank = sums[t] - cnt;             // exclusive global rank for f0
        int nc   = sums[255];
        for (int k = t; k < FEAT; k += 256)
            if (k >= nc) rowCol[k] = -1;      // tail: no crossing feature
        // pass 2: recompute val for crossing features, emit map entries
        const f32x4* cp = reinterpret_cast<const f32x4*>(x + f0);
        const f32x4* lp = reinterpret_cast<const f32x4*>(lambdas + f0);
        #pragma unroll
        for (int q = 0; q < 8; ++q) {
            f32x4 cv = cp[q], lv = lp[q];
            #pragma unroll
            for (int e = 0; e < 4; ++e) {
                int i = q*4 + e;
                if (mask & (1u << i)) {
                    float c = cv[e], r = rr[i];
                    float l = c - r, u = c + r;
                    float d = u - l;
                    float denom = (d > 0.f) ? d : 1.f;
                    float slope = u / denom;
                    float lam   = lv[e];
                    float val   = (lam >= slope) ? (-l * lam * 0.5f)
                                                 : (u * (1.f - lam) * 0.5f);
                    rowCol[rank] = f0 + i;
                    rowVal[rank] = val;
                    ++rank;
                }
            }
        }
    } else {
        // ---- zero-fill: contiguous 8192-float4 (128 KB) chunk per block ----
        const int j = bid - (NSTAT + 1);
        f32x4* eps = reinterpret_cast<f32x4*>(out + (size_t)G_GEN * FEAT);
        const size_t base = (size_t)j * (256 * 32);
        f32x4 z = {0.f, 0.f, 0.f, 0.f};
        #pragma unroll
        for (int i = 0; i < 32; ++i)
            eps[base + (size_t)i * 256 + t] = z;
    }
}

// Kernel B: pure scatter. Thread k: if rank k has a crossing feature, write its
// val at (G_GEN + k, col). Map comes from kernel A (stream-ordered, no sync needed).
__global__ void __launch_bounds__(256) kB(
    const int* __restrict__ rowCol, const float* __restrict__ rowVal,
    float* __restrict__ out)
{
    const int k = blockIdx.x * 256 + threadIdx.x;
    const int col = rowCol[k];
    if (col >= 0)
        out[(size_t)(G_GEN + k) * FEAT + col] = rowVal[k];
}

extern "C" void kernel_launch(void* const* d_in, const int* in_sizes, int n_in,
                              void* d_out, int out_size, void* d_ws, size_t ws_size,
                              hipStream_t stream) {
    const float* x       = (const float*)d_in[0];
    const float* lambdas = (const float*)d_in[1];
    float* out = (float*)d_out;

    int*   rowCol = (int*)d_ws;              // 32 KB
    float* rowVal = (float*)(rowCol + FEAT); // 32 KB

    kA<<<NSTAT + 1 + NFILL, 256, 0, stream>>>(x, lambdas, rowCol, rowVal, out);
    kB<<<FEAT / 256, 256, 0, stream>>>(rowCol, rowVal, out);
}

// Round 8
// 45.698 us; speedup vs baseline: 2.2485x; 2.2485x over previous
//
#include <hip/hip_runtime.h>

#define G_GEN 65
#define FEAT  8192     // 32*16*16
#define NSTAT 32       // stats blocks
#define NFILL 2016     // fill blocks; NSTAT+NFILL = 2048 = exact full-device residency
#define TOTF4 16777216 // FEAT*FEAT/4 float4 in the eps block

typedef float f32x4 __attribute__((ext_vector_type(4)));
typedef int   i32x4 __attribute__((ext_vector_type(4)));

// Kernel A (R5-proven structure, balanced grid):
//  bid <  32 : per-feature stats -> ws_val/ws_cross + base rows
//  bid >= 32 : zero-fill a contiguous ~130KB chunk (q/r split: 8322 or 8323 f4)
__global__ void __launch_bounds__(256) kA(
    const float* __restrict__ x, const float* __restrict__ lambdas,
    float* __restrict__ ws_val, int* __restrict__ ws_cross,
    float* __restrict__ out)
{
    const int bid = blockIdx.x;
    const int t   = threadIdx.x;

    if (bid < NSTAT) {
        const int f = bid * 256 + t;          // coalesced across lanes
        float c = x[f];                       // generator 0 = center
        float r = 0.f;
        #pragma unroll 8
        for (int g = 1; g < G_GEN; ++g) r += fabsf(x[g * FEAT + f]);
        float l = c - r, u = c + r;
        bool zero_m = (u <= 0.f);
        bool cross  = (!zero_m) && (l < 0.f);
        float d     = u - l;
        float denom = (d > 0.f) ? d : 1.f;
        float slope = u / denom;
        float lam   = lambdas[f];
        float val   = (lam >= slope) ? (-l * lam * 0.5f) : (u * (1.f - lam) * 0.5f);
        val = cross ? val : 0.f;
        float scale = zero_m ? 0.f : (cross ? lam : 1.f);
        ws_val[f]   = val;
        ws_cross[f] = cross ? 1 : 0;
        out[f] = c * scale + val;             // g == 0 row
        #pragma unroll 8
        for (int g = 1; g < G_GEN; ++g)
            out[g * FEAT + f] = x[g * FEAT + f] * scale;  // 2nd x read: L2-hot
    } else {
        // zero-fill: 16,777,216 f4 over 2016 blocks; q=8322, r=64
        const int  j  = bid - NSTAT;
        const long lo = (long)j * 8322 + (j < 64 ? j : 64);
        const long hi = lo + 8322 + (j < 64 ? 1 : 0);
        f32x4* eps = reinterpret_cast<f32x4*>(out + (size_t)G_GEN * FEAT);
        f32x4 z = {0.f, 0.f, 0.f, 0.f};
        for (long i = lo + t; i < hi; i += 256)
            eps[i] = z;
    }
}

// Kernel B: 1024-thread scan (wave64 shfl + 16 wave-sums) + scatter.
__global__ void __launch_bounds__(1024) kB(
    const float* __restrict__ ws_val,
    const int* __restrict__ ws_cross,
    float* __restrict__ out)
{
    __shared__ int wsum[16];
    const int t = threadIdx.x;
    const int base = t * 8;                   // 8 contiguous features per thread
    const i32x4* cp = reinterpret_cast<const i32x4*>(ws_cross + base);
    i32x4 c0 = cp[0], c1 = cp[1];
    int flags[8] = {c0[0], c0[1], c0[2], c0[3], c1[0], c1[1], c1[2], c1[3]};
    int local = 0;
    #pragma unroll
    for (int i = 0; i < 8; ++i) local += flags[i];

    const int lane = t & 63, w = t >> 6;      // 16 waves of 64
    int v = local;                            // wave-inclusive scan
    #pragma unroll
    for (int off = 1; off < 64; off <<= 1) {
        int n = __shfl_up(v, off, 64);
        if (lane >= off) v += n;
    }
    if (lane == 63) wsum[w] = v;
    __syncthreads();
    int wpre = 0;
    for (int j = 0; j < w; ++j) wpre += wsum[j];   // broadcast LDS reads
    int rank = wpre + v - local;              // exclusive prefix for this chunk

    const f32x4* vp = reinterpret_cast<const f32x4*>(ws_val + base);
    f32x4 v0 = vp[0], v1 = vp[1];
    float vals[8] = {v0[0], v0[1], v0[2], v0[3], v1[0], v1[1], v1[2], v1[3]};
    #pragma unroll
    for (int i = 0; i < 8; ++i) {
        if (flags[i]) {
            out[(size_t)(G_GEN + rank) * FEAT + (base + i)] = vals[i];
            ++rank;
        }
    }
}

extern "C" void kernel_launch(void* const* d_in, const int* in_sizes, int n_in,
                              void* d_out, int out_size, void* d_ws, size_t ws_size,
                              hipStream_t stream) {
    const float* x       = (const float*)d_in[0];
    const float* lambdas = (const float*)d_in[1];
    float* out = (float*)d_out;

    float* ws_val   = (float*)d_ws;
    int*   ws_cross = (int*)(ws_val + FEAT);

    kA<<<NSTAT + NFILL, 256, 0, stream>>>(x, lambdas, ws_val, ws_cross, out);
    kB<<<1, 1024, 0, stream>>>(ws_val, ws_cross, out);
}